// Round 4
// baseline (91.903 us; speedup 1.0000x reference)
//
#include <hip/hip_runtime.h>
#include <stdint.h>

#define N_EXPERTS 20
#define DIM 32
#define TMOE 512
#define MSTR 1032   // shorts per expert: 16B-aligned rows, stride_dw=516 ≡ 4 mod 32 -> 8-group bank spread
#define CSTR 36     // floats per expert in cs: 144 B (16B-aligned), bank = 4e+o -> spread

using frag_ab = __attribute__((ext_vector_type(8))) short;  // 8 bf16
using frag_cd = __attribute__((ext_vector_type(4))) float;  // 4 fp32

static __device__ __forceinline__ short f2bf(float f) {
    union { float f; uint32_t u; } v; v.f = f;
    uint32_t u = v.u;
    return (short)(uint16_t)((u + 0x7FFFu + ((u >> 16) & 1u)) >> 16);  // RNE
}
static __device__ __forceinline__ float bfl(uint32_t u) {
    union { uint32_t u; float f; } v; v.u = u << 16; return v.f;
}
static __device__ __forceinline__ float bfh(uint32_t u) {
    union { uint32_t u; float f; } v; v.u = u & 0xFFFF0000u; return v.f;
}

// Single fused kernel: per-block MFMA build of M[e]=W0[e]@W1[e] (bf16) and
// c[e]=W0[e]@b1[e]+b0[e] (f32) into LDS, then one-thread-one-sample VALU
// matvec + L2 normalize. No workspace, no second dispatch.
__global__ __launch_bounds__(TMOE) void k_moe(
    const float* __restrict__ x, const int* __restrict__ pos,
    const float* __restrict__ W1, const float* __restrict__ b1,
    const float* __restrict__ W0, const float* __restrict__ b0,
    float* __restrict__ out, int B)
{
    __shared__ unsigned short Ms[N_EXPERTS * MSTR];   // 41,280 B
    __shared__ float cs[N_EXPERTS * CSTR];            //  2,880 B

    int t = threadIdx.x;
    int s = blockIdx.x * TMOE + t;
    int lane = t & 63, wave = t >> 6;
    int n = lane & 15, q = lane >> 4;

    // ---- x/pos prefetch first: global pipe overlaps the M-build ----
    float4 xv[8];
    int e = 0;
    bool live = (s < B);
    if (live) {
        const float4* xp = (const float4*)(x + (size_t)s * 32);
        #pragma unroll
        for (int i = 0; i < 8; i++) xv[i] = xp[i];
        e = pos[s];
    }

    // ---- fused M-build: 40 tasks (expert, row-half), 5 per wave ----
    #pragma unroll 1
    for (int task = wave; task < 2 * N_EXPERTS; task += TMOE / 64) {
        int te = task >> 1, r = task & 1;
        const float* w0 = W0 + te * 1024;
        const float* w1 = W1 + te * 1024;

        // A-frag (verified layout): A[m=lane&15][k=q*8+j] = W0[16r+m][k]
        const float* ap = w0 + (16 * r + n) * 32 + q * 8;
        float4 a0 = *(const float4*)ap;
        float4 a1 = *(const float4*)(ap + 4);
        frag_ab af;
        af[0]=f2bf(a0.x); af[1]=f2bf(a0.y); af[2]=f2bf(a0.z); af[3]=f2bf(a0.w);
        af[4]=f2bf(a1.x); af[5]=f2bf(a1.y); af[6]=f2bf(a1.z); af[7]=f2bf(a1.w);

        // B-frags: B[k=q*8+j][col] = W1[k][col], cols n and n+16; bb = b1 in col 0
        frag_ab bf0, bf1, bb;
        #pragma unroll
        for (int j = 0; j < 8; j++) {
            int k = q * 8 + j;
            bf0[j] = f2bf(w1[k * 32 + n]);
            bf1[j] = f2bf(w1[k * 32 + 16 + n]);
            short bv = f2bf(b1[te * 32 + k]);
            bb[j] = (n == 0) ? bv : (short)0;
        }
        frag_cd z = {0.f, 0.f, 0.f, 0.f};
        frag_cd d0 = __builtin_amdgcn_mfma_f32_16x16x32_bf16(af, bf0, z, 0, 0, 0);
        frag_cd d1 = __builtin_amdgcn_mfma_f32_16x16x32_bf16(af, bf1, z, 0, 0, 0);
        frag_cd dc = __builtin_amdgcn_mfma_f32_16x16x32_bf16(af, bb, z, 0, 0, 0);

        // C/D (verified): col = lane&15, row = q*4 + reg
        unsigned short* mrow = Ms + te * MSTR;
        #pragma unroll
        for (int reg = 0; reg < 4; reg++) {
            int row = 16 * r + q * 4 + reg;
            mrow[row * 32 + n]      = (unsigned short)f2bf(d0[reg]);
            mrow[row * 32 + 16 + n] = (unsigned short)f2bf(d1[reg]);
        }
        if (n == 0) {
            #pragma unroll
            for (int reg = 0; reg < 4; reg++) {
                int row = 16 * r + q * 4 + reg;
                cs[te * CSTR + row] = dc[reg] + b0[te * 32 + row];
            }
        }
    }
    __syncthreads();
    if (!live) return;

    const unsigned short* M = Ms + e * MSTR;
    const float4* cp = (const float4*)(cs + e * CSTR);

    // acc init = c[e] (bias of the collapsed affine map)
    float acc[32];
    #pragma unroll
    for (int g = 0; g < 8; g++) {
        float4 cv = cp[g];
        acc[4*g+0] = cv.x; acc[4*g+1] = cv.y; acc[4*g+2] = cv.z; acc[4*g+3] = cv.w;
    }

    // matvec: fully unrolled so acc[] stays in VGPRs (no dynamic indexing)
    #pragma unroll
    for (int o = 0; o < 32; o++) {
        const uint4* mp = (const uint4*)(M + o * 32);
        float a = acc[o];
        #pragma unroll
        for (int kk = 0; kk < 4; kk++) {
            uint4 m = mp[kk];
            float4 x0 = xv[2*kk], x1 = xv[2*kk + 1];
            a += bfl(m.x) * x0.x + bfh(m.x) * x0.y
               + bfl(m.y) * x0.z + bfh(m.y) * x0.w
               + bfl(m.z) * x1.x + bfh(m.z) * x1.y
               + bfl(m.w) * x1.z + bfh(m.w) * x1.w;
        }
        acc[o] = a;
    }

    float ss = 0.f;
    #pragma unroll
    for (int o = 0; o < 32; o++) ss += acc[o] * acc[o];
    float sc = rsqrtf(fmaxf(ss, 1e-24f));   // == 1/max(||v||, 1e-12)

    float4* op = (float4*)(out + (size_t)s * 32);
    #pragma unroll
    for (int g = 0; g < 8; g++) {
        float4 v;
        v.x = acc[4*g+0] * sc;
        v.y = acc[4*g+1] * sc;
        v.z = acc[4*g+2] * sc;
        v.w = acc[4*g+3] * sc;
        op[g] = v;
    }
}

extern "C" void kernel_launch(void* const* d_in, const int* in_sizes, int n_in,
                              void* d_out, int out_size, void* d_ws, size_t ws_size,
                              hipStream_t stream) {
    const float* x  = (const float*)d_in[0];
    const float* W1 = (const float*)d_in[1];
    const float* b1 = (const float*)d_in[2];
    const float* W0 = (const float*)d_in[3];
    const float* b0 = (const float*)d_in[4];
    const int*  pos = (const int*)d_in[5];
    float* out = (float*)d_out;
    int B = in_sizes[0] / DIM;   // 131072

    int nblk = (B + TMOE - 1) / TMOE;   // 256 == 1 block/CU
    k_moe<<<nblk, TMOE, 0, stream>>>(x, pos, W1, b1, W0, b0, out, B);
}

// Round 5
// 89.926 us; speedup vs baseline: 1.0220x; 1.0220x over previous
//
#include <hip/hip_runtime.h>
#include <stdint.h>

#define N_EXPERTS 20
#define DIM 32
#define SPB 256            // samples per block (== block threads)
#define MAIN_T 256
#define MROW 40            // LDS M row stride in shorts (80 B: 16B-aligned rows, near-conflict-free b128)
#define MAX_TILES 48

using frag_ab = __attribute__((ext_vector_type(8))) short;  // 8 bf16
using frag_cd = __attribute__((ext_vector_type(4))) float;  // 4 fp32

static __device__ __forceinline__ short f2bf(float f) {
    union { float f; uint32_t u; } v; v.f = f;
    uint32_t u = v.u;
    return (short)(uint16_t)((u + 0x7FFFu + ((u >> 16) & 1u)) >> 16);  // RNE
}

// ---------------- K1: combined-weight precompute ----------------
// M[e] = W0[e] @ W1[e]  (bf16), c[e] = W0[e] @ b1[e] + b0[e]  (fp32)
__global__ __launch_bounds__(256) void k_prep(
    const float* __restrict__ W1, const float* __restrict__ b1,
    const float* __restrict__ W0, const float* __restrict__ b0,
    unsigned short* __restrict__ Mbf, float* __restrict__ cvec)
{
    __shared__ float s1[1024], s0[1024];
    int e = blockIdx.x, t = threadIdx.x;
    const float* w1 = W1 + e * 1024;
    const float* w0 = W0 + e * 1024;
    for (int i = t; i < 1024; i += 256) { s1[i] = w1[i]; s0[i] = w0[i]; }
    __syncthreads();
    for (int idx = t; idx < 1024; idx += 256) {
        int o = idx >> 5, i = idx & 31;
        float s = 0.f;
        #pragma unroll
        for (int k = 0; k < 32; k++) s += s0[o*32 + k] * s1[k*32 + i];
        Mbf[e*1024 + o*32 + i] = (unsigned short)f2bf(s);
    }
    if (t < DIM) {
        float s = b0[e*32 + t];
        #pragma unroll
        for (int k = 0; k < 32; k++) s += s0[t*32 + k] * b1[e*32 + k];
        cvec[e*32 + t] = s;
    }
}

// ---------------- K2: block-local bucket + MFMA + normalize ----------------
__global__ __launch_bounds__(MAIN_T) void k_moe(
    const float* __restrict__ x, const int* __restrict__ pos,
    const unsigned short* __restrict__ Mbf, const float* __restrict__ cvec,
    float* __restrict__ out, int B)
{
    __shared__ unsigned short Ms[N_EXPERTS * 32 * MROW];   // 51200 B
    __shared__ float cs[N_EXPERTS * 32];
    __shared__ int hist[N_EXPERTS];
    __shared__ int lstart[N_EXPERTS + 1];
    __shared__ int cursor[N_EXPERTS];
    __shared__ int lidx[SPB];
    __shared__ int tileE[MAX_TILES], tileB[MAX_TILES];
    __shared__ int ntiles;

    int t = threadIdx.x;
    int base = blockIdx.x * SPB;
    int S = min(SPB, B - base);
    if (S <= 0) return;

    if (t < N_EXPERTS) hist[t] = 0;
    __syncthreads();

    // stage M (20*1024 shorts = 10240 dwords) into padded LDS rows + cs
    {
        const uint32_t* msrc = (const uint32_t*)Mbf;
        uint32_t* mdst = (uint32_t*)Ms;
        for (int d = t; d < N_EXPERTS * 512; d += MAIN_T) {
            int e = d >> 9, rem = d & 511;
            int n = rem >> 4, c = rem & 15;
            mdst[e * (32 * MROW / 2) + n * (MROW / 2) + c] = msrc[d];
        }
        for (int i = t; i < N_EXPERTS * 32; i += MAIN_T) cs[i] = cvec[i];
    }
    // histogram (1 sample / thread)
    int my_e = -1;
    if (t < S) {
        my_e = pos[base + t];
        atomicAdd(&hist[my_e], 1);
    }
    __syncthreads();

    int lane = t & 63, wave = t >> 6;

    // wave-0 shuffle scan: bucket starts + tile table
    if (wave == 0) {
        int e = lane;
        int h = (e < N_EXPERTS) ? hist[e] : 0;
        int s = h;
        #pragma unroll
        for (int d = 1; d < 32; d <<= 1) { int v = __shfl_up(s, d); if (lane >= d) s += v; }
        int pre = s - h;                       // exclusive prefix of counts
        int ntl = (h + 15) >> 4;
        int ts = ntl;
        #pragma unroll
        for (int d = 1; d < 32; d <<= 1) { int v = __shfl_up(ts, d); if (lane >= d) ts += v; }
        int tpre = ts - ntl;                   // exclusive prefix of tile counts
        if (e < N_EXPERTS) {
            lstart[e] = pre; cursor[e] = pre;
            for (int k = 0; k < ntl; k++) { tileE[tpre + k] = e; tileB[tpre + k] = pre + 16 * k; }
            if (e == N_EXPERTS - 1) { lstart[N_EXPERTS] = pre + h; ntiles = tpre + ntl; }
        }
    }
    __syncthreads();

    // scatter local indices
    if (t < S) {
        int slot = atomicAdd(&cursor[my_e], 1);
        lidx[slot] = t;
    }
    __syncthreads();

    int nt = ntiles;
    int n = lane & 15, q = lane >> 4;

    // software-pipelined tile loop (prefetch next tile's x)
    int ti = wave;
    float4 xa, xb;
    int cur_e = 0, cur_tb = 0, cur_bend = 0;
    if (ti < nt) {
        cur_e = tileE[ti]; cur_tb = tileB[ti]; cur_bend = lstart[cur_e + 1];
        int slot = min(cur_tb + n, cur_bend - 1);
        int l = lidx[slot];
        const float* xr = x + (size_t)(base + l) * 32 + q * 8;
        xa = *(const float4*)xr; xb = *(const float4*)(xr + 4);
    }
    for (; ti < nt; ti += 4) {
        int e = cur_e, tb = cur_tb, bend = cur_bend;
        float4 a0 = xa, a1 = xb;
        int tj = ti + 4;
        if (tj < nt) {
            cur_e = tileE[tj]; cur_tb = tileB[tj]; cur_bend = lstart[cur_e + 1];
            int slot = min(cur_tb + n, cur_bend - 1);
            int l = lidx[slot];
            const float* xr = x + (size_t)(base + l) * 32 + q * 8;
            xa = *(const float4*)xr; xb = *(const float4*)(xr + 4);
        }

        // B-fragments from LDS: B[k=q*8+j][col] = M[col][k]
        const unsigned short* mrow = Ms + e * 32 * MROW;
        frag_ab bf0 = *(const frag_ab*)(mrow + n * MROW + q * 8);
        frag_ab bf1 = *(const frag_ab*)(mrow + (n + 16) * MROW + q * 8);
        float c0 = cs[e * 32 + n];
        float c1 = cs[e * 32 + 16 + n];

        frag_ab af;
        af[0] = f2bf(a0.x); af[1] = f2bf(a0.y); af[2] = f2bf(a0.z); af[3] = f2bf(a0.w);
        af[4] = f2bf(a1.x); af[5] = f2bf(a1.y); af[6] = f2bf(a1.z); af[7] = f2bf(a1.w);

        frag_cd z = {0.f, 0.f, 0.f, 0.f};
        frag_cd d0 = __builtin_amdgcn_mfma_f32_16x16x32_bf16(af, bf0, z, 0, 0, 0);
        frag_cd d1 = __builtin_amdgcn_mfma_f32_16x16x32_bf16(af, bf1, z, 0, 0, 0);

        // C/D: col = lane&15 (=n), row-in-tile = q*4 + r
        #pragma unroll
        for (int r = 0; r < 4; r++) {
            int os = tb + q * 4 + r;
            float v0 = d0[r] + c0;
            float v1 = d1[r] + c1;
            float ss = v0 * v0 + v1 * v1;
            ss += __shfl_xor(ss, 1);
            ss += __shfl_xor(ss, 2);
            ss += __shfl_xor(ss, 4);
            ss += __shfl_xor(ss, 8);          // 32-dim sum of squares per sample
            float sc = rsqrtf(fmaxf(ss, 1e-24f));
            if (os < bend) {
                int lo = lidx[os];
                float* op = out + (size_t)(base + lo) * 32;
                op[n]      = v0 * sc;
                op[16 + n] = v1 * sc;
            }
        }
    }
}

extern "C" void kernel_launch(void* const* d_in, const int* in_sizes, int n_in,
                              void* d_out, int out_size, void* d_ws, size_t ws_size,
                              hipStream_t stream) {
    const float* x  = (const float*)d_in[0];
    const float* W1 = (const float*)d_in[1];
    const float* b1 = (const float*)d_in[2];
    const float* W0 = (const float*)d_in[3];
    const float* b0 = (const float*)d_in[4];
    const int*  pos = (const int*)d_in[5];
    float* out = (float*)d_out;
    int B = in_sizes[0] / DIM;   // 131072

    char* ws = (char*)d_ws;
    unsigned short* Mbf = (unsigned short*)ws;                       // 20*1024 shorts
    float* cvec = (float*)(ws + (size_t)N_EXPERTS * 1024 * 2);       // 20*32 floats

    k_prep<<<N_EXPERTS, 256, 0, stream>>>(W1, b1, W0, b0, Mbf, cvec);
    int nblk = (B + SPB - 1) / SPB;
    k_moe<<<nblk, MAIN_T, 0, stream>>>(x, pos, Mbf, cvec, out, B);
}